// Round 13
// baseline (422.155 us; speedup 1.0000x reference)
//
#include <hip/hip_runtime.h>

#define NROWS  65536
#define CDIM   128
#define MKEYS  1024
#define BROWS  256    // rows per block (1 block/CU -- proven residency)
#define ITROWS 64     // rows per iteration (4 tiles of 16)
#define NITER  (BROWS / ITROWS)
#define CANDCAP 8

typedef _Float16 half8 __attribute__((ext_vector_type(8)));
typedef _Float16 half4 __attribute__((ext_vector_type(4)));
typedef float    floatx4 __attribute__((ext_vector_type(4)));

union FU { float f; unsigned u; };

#define MFMA16 __builtin_amdgcn_mfma_f32_16x16x32_f16

// ---------------- Kernel A: convert keys fp32 -> fp16 in MFMA-fragment order --------
// Layout: for key k, dim d:  g=k>>4, n=k&15, f=d>>5, q8=(d&31)>>3, e=d&7
//   kh[ ((g*4+f)*64 + q8*16 + n)*8 + e ] = (fp16) keys[k][d]
__global__ __launch_bounds__(256) void cvt_keys_kernel(const float* __restrict__ keys,
                                                       _Float16* __restrict__ kh) {
    int i  = blockIdx.x * 256 + threadIdx.x;        // 32768 threads
    int k  = i >> 5;                                // key 0..1023
    int d0 = (i & 31) * 4;                          // dim 0,4,...,124
    float4 f4 = *(const float4*)(keys + (long)k * CDIM + d0);
    half4 hv;
    hv[0] = (_Float16)f4.x; hv[1] = (_Float16)f4.y;
    hv[2] = (_Float16)f4.z; hv[3] = (_Float16)f4.w;
    int g = k >> 4, n = k & 15;
    int f = d0 >> 5, q8 = (d0 & 31) >> 3, e = d0 & 7;
    long idx = ((long)((g * 4 + f) * 64 + q8 * 16 + n)) * 8 + e;
    *(half4*)(kh + idx) = hv;
}

// ---------------- Kernel B: keys-in-registers, 64-row iterations, single pass --------
// R13 = R12 + {4 tiles/iter, top-2 replaces pass2, async q-prefetch}.
// Rigor chain (R8-proven, absmax 0.0): thr = M1 - 2*e1 - slack; every per-thread
// top-1 with s~ >= thr is a candidate; a thread's exact 2nd max >= thr forces full
// exact rescan of that row. True argmax has s~ >= thr, so it is either some thread's
// pushed top-1 or covered by the rescan. cnt==1 -> exact argmax; cnt>1 -> exact fp32
// rescore (ties -> lowest key); cap overflow -> rescan.
__global__ __launch_bounds__(512, 2) void gather_main(
    const float* __restrict__ q,      // trend_representation (65536x128)
    const float* __restrict__ rep,    // representation
    const float* __restrict__ keys,   // fp32 keys (1024x128)
    const float* __restrict__ vals,   // fp32 values
    const _Float16* __restrict__ kh,  // fp16 keys, fragment order (ws)
    float* __restrict__ out)          // [131072]: keys_g then values_g
{
    __shared__ _Float16 qh[4][16][128];            // 16 KB: 4 tiles
    __shared__ float qss[ITROWS];                  // per-row sumsq (shfl-reduced)
    __shared__ float wtv[8][4][16];                // per-wave per-tile per-row max
    __shared__ int   candCnt[ITROWS];
    __shared__ int   candKey[ITROWS][CANDCAP];
    __shared__ int   rowOvf[ITROWS];
    __shared__ unsigned long long rowBest[ITROWS];
    __shared__ int   rowIdxAll[BROWS];

    const int t    = threadIdx.x;     // 0..511
    const int w    = t >> 6;          // wave 0..7 (owns keys w*128..w*128+127)
    const int lane = t & 63;
    const int n    = lane & 15;       // q-row (C col) within tile
    const int quad = lane >> 4;       // key sub-slice / C row group
    const long blk0 = (long)blockIdx.x * BROWS;

    // ---- preload this wave's 128 keys into 32 half8 registers (one burst) ----
    const _Float16* kb = kh + (long)w * 16384 + lane * 8;
#define KD(g) k##g##0, k##g##1, k##g##2, k##g##3
    half8 KD(0), KD(1), KD(2), KD(3), KD(4), KD(5), KD(6), KD(7);
#define KL(g) \
    k##g##0 = *(const half8*)(kb + ((g)*4 + 0) * 512); \
    k##g##1 = *(const half8*)(kb + ((g)*4 + 1) * 512); \
    k##g##2 = *(const half8*)(kb + ((g)*4 + 2) * 512); \
    k##g##3 = *(const half8*)(kb + ((g)*4 + 3) * 512);
    KL(0) KL(1) KL(2) KL(3) KL(4) KL(5) KL(6) KL(7)

#define ENCMAX(v_, key_, r_) {                                             \
        FU su; su.f = (v_);                                                \
        unsigned ord = (su.u & 0x80000000u) ? ~su.u : (su.u | 0x80000000u);\
        unsigned long long enc = ((unsigned long long)ord << 32)           \
                               | (unsigned)(1023 - (key_));                \
        atomicMax(&rowBest[r_], enc); }

    // row-state init
    if (t < ITROWS) { candCnt[t] = 0; rowOvf[t] = 0; rowBest[t] = 0ull; }

    // ---- prologue: prefetch iteration-0 q rows into registers ----
    const int rr0 = t >> 4, c8 = t & 15;   // this thread stages rows rr0 and rr0+32
    float4 pa0, pb0, pa1, pb1;
    {
        const float4* s0p = (const float4*)(q + (blk0 + rr0) * CDIM + c8 * 8);
        pa0 = s0p[0]; pb0 = s0p[1];
        const float4* s1p = (const float4*)(q + (blk0 + rr0 + 32) * CDIM + c8 * 8);
        pa1 = s1p[0]; pb1 = s1p[1];
    }

    for (int iter = 0; iter < NITER; ++iter) {
        const long g0 = blk0 + (long)iter * ITROWS;

        // ---- stage: prefetched regs -> qh (swizzled) + qss (16-lane shfl) ----
        {
#define WRITEQ(r_, a_, b_) {                                             \
            half8 hv;                                                    \
            hv[0]=(_Float16)(a_).x; hv[1]=(_Float16)(a_).y;              \
            hv[2]=(_Float16)(a_).z; hv[3]=(_Float16)(a_).w;              \
            hv[4]=(_Float16)(b_).x; hv[5]=(_Float16)(b_).y;              \
            hv[6]=(_Float16)(b_).z; hv[7]=(_Float16)(b_).w;              \
            int phys = c8 ^ ((r_) & 7);                                  \
            *(half8*)&qh[(r_) >> 4][(r_) & 15][phys * 8] = hv; }
            WRITEQ(rr0,      pa0, pb0);
            WRITEQ(rr0 + 32, pa1, pb1);
            float s0 = pa0.x*pa0.x + pa0.y*pa0.y + pa0.z*pa0.z + pa0.w*pa0.w
                     + pb0.x*pb0.x + pb0.y*pb0.y + pb0.z*pb0.z + pb0.w*pb0.w;
            float s1 = pa1.x*pa1.x + pa1.y*pa1.y + pa1.z*pa1.z + pa1.w*pa1.w
                     + pb1.x*pb1.x + pb1.y*pb1.y + pb1.z*pb1.z + pb1.w*pb1.w;
            s0 += __shfl_xor(s0, 1); s0 += __shfl_xor(s0, 2);
            s0 += __shfl_xor(s0, 4); s0 += __shfl_xor(s0, 8);
            s1 += __shfl_xor(s1, 1); s1 += __shfl_xor(s1, 2);
            s1 += __shfl_xor(s1, 4); s1 += __shfl_xor(s1, 8);
            if (c8 == 0) { qss[rr0] = s0; qss[rr0 + 32] = s1; }
        }
        __syncthreads();                                               // B1

        // ---- async prefetch of next iteration's q (lands during slab) ----
        if (iter + 1 < NITER) {
            const long gn = g0 + ITROWS;
            const float4* s0p = (const float4*)(q + (gn + rr0) * CDIM + c8 * 8);
            pa0 = s0p[0]; pb0 = s0p[1];
            const float4* s1p = (const float4*)(q + (gn + rr0 + 32) * CDIM + c8 * 8);
            pa1 = s1p[0]; pb1 = s1p[1];
        }

        // ---- single MFMA pass over 4 tiles with exact branch-free top-2 ----
        float b1t0 = -3.4e38f, b2t0 = -3.4e38f; int i1t0 = 0;
        float b1t1 = -3.4e38f, b2t1 = -3.4e38f; int i1t1 = 0;
        float b1t2 = -3.4e38f, b2t2 = -3.4e38f; int i1t2 = 0;
        float b1t3 = -3.4e38f, b2t3 = -3.4e38f; int i1t3 = 0;
        const int x = n & 7;
        const int fp0 = ((0 * 4 + quad) ^ x) * 8;
        const int fp1 = ((1 * 4 + quad) ^ x) * 8;
        const int fp2 = ((2 * 4 + quad) ^ x) * 8;
        const int fp3 = ((3 * 4 + quad) ^ x) * 8;

#define TOP2(s_, b1_, b2_, i1_, keyb_) {                                      \
        float s0_ = s_[0], s1_ = s_[1], s2_ = s_[2], s3_ = s_[3];             \
        float m01 = fmaxf(s0_, s1_), m23 = fmaxf(s2_, s3_);                   \
        int   j01 = (s1_ > s0_) ? 1 : 0, j23 = (s3_ > s2_) ? 3 : 2;           \
        float c1 = fmaxf(m01, m23);                                           \
        int   jc = (m23 > m01) ? j23 : j01;                                   \
        float c2 = fmaxf(fminf(m01, m23),                                     \
                         fmaxf(fminf(s0_, s1_), fminf(s2_, s3_)));            \
        bool better = c1 > b1_;                                               \
        b2_ = fmaxf(fminf(b1_, c1), fmaxf(b2_, c2));                          \
        b1_ = fmaxf(b1_, c1);                                                 \
        i1_ = better ? ((keyb_) + jc) : i1_; }

#define GRP(T, g) { floatx4 acc = {0.f, 0.f, 0.f, 0.f};                       \
        acc = MFMA16(k##g##0, qf0, acc, 0, 0, 0);                             \
        acc = MFMA16(k##g##1, qf1, acc, 0, 0, 0);                             \
        acc = MFMA16(k##g##2, qf2, acc, 0, 0, 0);                             \
        acc = MFMA16(k##g##3, qf3, acc, 0, 0, 0);                             \
        int keyb = ((w * 8 + (g)) << 4) + (quad << 2);                        \
        TOP2(acc, b1t##T, b2t##T, i1t##T, keyb) }

#define TILE_PASS(T) {                                                        \
        half8 qf0 = *(const half8*)&qh[T][n][fp0];                            \
        half8 qf1 = *(const half8*)&qh[T][n][fp1];                            \
        half8 qf2 = *(const half8*)&qh[T][n][fp2];                            \
        half8 qf3 = *(const half8*)&qh[T][n][fp3];                            \
        GRP(T,0) GRP(T,1) GRP(T,2) GRP(T,3)                                   \
        GRP(T,4) GRP(T,5) GRP(T,6) GRP(T,7) }

        TILE_PASS(0) TILE_PASS(1) TILE_PASS(2) TILE_PASS(3)

        // ---- merge row max across quads (value only), publish per wave ----
#define MRG(T) { float m_ = b1t##T;                                           \
        m_ = fmaxf(m_, __shfl_xor(m_, 16));                                   \
        m_ = fmaxf(m_, __shfl_xor(m_, 32));                                   \
        if (lane < 16) wtv[w][T][n] = m_; }
        MRG(0) MRG(1) MRG(2) MRG(3)
        __syncthreads();                                               // B2

        // ---- thresholds (redundant per thread) + candidate push ----
#define PUSH_T(T) {                                                           \
        float M1 = wtv[0][T][n];                                              \
        _Pragma("unroll")                                                     \
        for (int ww = 1; ww < 8; ++ww) M1 = fmaxf(M1, wtv[ww][T][n]);         \
        float thr_ = M1 - 2.f * (0.0168f * sqrtf(qss[(T)*16 + n]) + 0.002f)   \
                   - 0.02f;                                                   \
        int r_ = (T) * 16 + n;                                                \
        if (b1t##T >= thr_) {                                                 \
            int p_ = atomicAdd(&candCnt[r_], 1);                              \
            if (p_ < CANDCAP) candKey[r_][p_] = i1t##T; else rowOvf[r_] = 1;  \
        }                                                                     \
        if (b2t##T >= thr_) rowOvf[r_] = 1; }
        PUSH_T(0) PUSH_T(1) PUSH_T(2) PUSH_T(3)
        __syncthreads();                                               // B3

        // ---- ballot-gated sparse exact resolve (64-bit row masks) ----
        {
            int cntL = candCnt[lane], ovL = rowOvf[lane];
            unsigned long long needMask = __ballot(!ovL && cntL > 1);
            unsigned long long ovfMask  = __ballot(ovL != 0);
            // multi-candidate rows: wave w rescores slot w (64-lane coalesced dot)
            while (needMask) {
                int rb = __builtin_ctzll(needMask); needMask &= needMask - 1;
                if (w < candCnt[rb]) {
                    int key = candKey[rb][w];
                    const float2 xq = *(const float2*)(q + (g0 + rb) * CDIM + lane * 2);
                    const float2 xk = *(const float2*)(keys + (long)key * CDIM + lane * 2);
                    float v = xq.x * xk.x + xq.y * xk.y;
                    v += __shfl_xor(v, 1);  v += __shfl_xor(v, 2);
                    v += __shfl_xor(v, 4);  v += __shfl_xor(v, 8);
                    v += __shfl_xor(v, 16); v += __shfl_xor(v, 32);
                    if (lane == 0) ENCMAX(v, key, rb);
                }
            }
            // overflow rows: exact full rescan (rigor path, rare)
            while (ovfMask) {
                int rb = __builtin_ctzll(ovfMask); ovfMask &= ovfMask - 1;
                int grp = t >> 4, l16 = t & 15;
                const float* qp = q + (g0 + rb) * CDIM + l16 * 8;
                float4 xa = *(const float4*)(qp), xb = *(const float4*)(qp + 4);
                for (int it = 0; it < 32; ++it) {
                    int key = it * 32 + grp;
                    const float* kp2 = keys + (long)key * CDIM + l16 * 8;
                    float4 ya = *(const float4*)(kp2), yb = *(const float4*)(kp2 + 4);
                    float v = xa.x*ya.x + xa.y*ya.y + xa.z*ya.z + xa.w*ya.w
                            + xb.x*yb.x + xb.y*yb.y + xb.z*yb.z + xb.w*yb.w;
                    v += __shfl_xor(v, 1); v += __shfl_xor(v, 2);
                    v += __shfl_xor(v, 4); v += __shfl_xor(v, 8);
                    if (l16 == 0) ENCMAX(v, key, rb);
                }
            }
        }
        __syncthreads();                                               // B4

        // ---- decode + same-owner state reset (safe pre-B1 of next iter) ----
        if (t < ITROWS) {
            int cnt = candCnt[t];
            rowIdxAll[iter * ITROWS + t] =
                (!rowOvf[t] && cnt == 1)
                    ? candKey[t][0]
                    : (1023 - (int)(unsigned)(rowBest[t] & 0xffffffffull));
            candCnt[t] = 0; rowOvf[t] = 0; rowBest[t] = 0ull;
        }
    }
    __syncthreads();

    // ---- batched gather: 8 passes x 32 rows, 16 lanes per row ----
    {
        int l16 = t & 15;
        #pragma unroll 1
        for (int pass = 0; pass < BROWS / 32; ++pass) {
            int row = pass * 32 + (t >> 4);
            int idx = rowIdxAll[row];
            long g = blk0 + row;
            const float* qp  = q    + g * CDIM + l16 * 8;
            const float* kp2 = keys + (long)idx * CDIM + l16 * 8;
            const float* rp  = rep  + g * CDIM + l16 * 8;
            const float* vp  = vals + (long)idx * CDIM + l16 * 8;
            float4 qa = *(const float4*)(qp),  qb = *(const float4*)(qp + 4);
            float4 ka = *(const float4*)(kp2), kb4 = *(const float4*)(kp2 + 4);
            float4 ra = *(const float4*)(rp),  rb = *(const float4*)(rp + 4);
            float4 va = *(const float4*)(vp),  vb = *(const float4*)(vp + 4);
            float d0 = qa.x-ka.x, d1 = qa.y-ka.y, d2 = qa.z-ka.z, d3 = qa.w-ka.w;
            float d4 = qb.x-kb4.x, d5 = qb.y-kb4.y, d6 = qb.z-kb4.z, d7 = qb.w-kb4.w;
            float kg = d0*d0+d1*d1+d2*d2+d3*d3+d4*d4+d5*d5+d6*d6+d7*d7;
            float e0 = ra.x-va.x, e1 = ra.y-va.y, e2 = ra.z-va.z, e3 = ra.w-va.w;
            float e4 = rb.x-vb.x, e5 = rb.y-vb.y, e6 = rb.z-vb.z, e7 = rb.w-vb.w;
            float vg = e0*e0+e1*e1+e2*e2+e3*e3+e4*e4+e5*e5+e6*e6+e7*e7;
            kg += __shfl_xor(kg, 1); kg += __shfl_xor(kg, 2);
            kg += __shfl_xor(kg, 4); kg += __shfl_xor(kg, 8);
            vg += __shfl_xor(vg, 1); vg += __shfl_xor(vg, 2);
            vg += __shfl_xor(vg, 4); vg += __shfl_xor(vg, 8);
            if (l16 == 0) { out[g] = kg; out[NROWS + g] = vg; }
        }
    }
}

extern "C" void kernel_launch(void* const* d_in, const int* in_sizes, int n_in,
                              void* d_out, int out_size, void* d_ws, size_t ws_size,
                              hipStream_t stream) {
    const float* q    = (const float*)d_in[0];  // trend_representation
    const float* rep  = (const float*)d_in[1];  // representation
    const float* keys = (const float*)d_in[2];
    const float* vals = (const float*)d_in[3];
    _Float16* kh = (_Float16*)d_ws;             // 256 KB fp16 key cache (fragment order)

    cvt_keys_kernel<<<128, 256, 0, stream>>>(keys, kh);
    gather_main<<<NROWS / BROWS, 512, 0, stream>>>(q, rep, keys, vals, kh,
                                                   (float*)d_out);
}

// Round 14
// 167.506 us; speedup vs baseline: 2.5202x; 2.5202x over previous
//
#include <hip/hip_runtime.h>

#define NROWS  65536
#define CDIM   128
#define MKEYS  1024
#define BROWS  256    // rows per block (1 block/CU -- proven residency)
#define TROWS  16
#define NPAIRS 8      // 8 pairs x 32 rows
#define CANDCAP 8

typedef _Float16 half8 __attribute__((ext_vector_type(8)));
typedef _Float16 half4 __attribute__((ext_vector_type(4)));
typedef float    floatx4 __attribute__((ext_vector_type(4)));

union FU { float f; unsigned u; };

#define MFMA16 __builtin_amdgcn_mfma_f32_16x16x32_f16

// fire-and-forget global->LDS DMA: per-lane global src, wave-uniform LDS base,
// HW writes base + lane*16 (R5-proven-correct pattern).
__device__ __forceinline__ void gl_lds16(const _Float16* g, _Float16* l) {
    __builtin_amdgcn_global_load_lds(
        (__attribute__((address_space(1))) unsigned int*)g,
        (__attribute__((address_space(3))) unsigned int*)l, 16, 0, 0);
}

// ---------------- Kernel A: convert keys AND q to fp16 --------------------------------
// blocks [0,128): keys -> kh in MFMA-fragment order (as before).
// blocks [128,128+4096): q -> qhg fp16, PRE-SWIZZLED within each row
//   (qhg[row][p*8..] = q[row][(p^(row&7))*8..]) so linear DMA into LDS reproduces
//   the swizzled qh layout; also per-row sumsq -> qssg.
__global__ __launch_bounds__(256) void cvt_kernel(const float* __restrict__ keys,
                                                  const float* __restrict__ q,
                                                  _Float16* __restrict__ kh,
                                                  _Float16* __restrict__ qhg,
                                                  float* __restrict__ qssg) {
    int bid = blockIdx.x, t = threadIdx.x;
    if (bid < 128) {
        int i = bid * 256 + t, k = i >> 5, d0 = (i & 31) * 4;
        float4 f4 = *(const float4*)(keys + (long)k * CDIM + d0);
        half4 hv;
        hv[0] = (_Float16)f4.x; hv[1] = (_Float16)f4.y;
        hv[2] = (_Float16)f4.z; hv[3] = (_Float16)f4.w;
        int g = k >> 4, n = k & 15;
        int f = d0 >> 5, q8 = (d0 & 31) >> 3, e = d0 & 7;
        long idx = ((long)((g * 4 + f) * 64 + q8 * 16 + n)) * 8 + e;
        *(half4*)(kh + idx) = hv;
    } else {
        long row = (long)(bid - 128) * 16 + (t >> 4);
        int l16 = t & 15;
        const float4* src = (const float4*)(q + row * CDIM + l16 * 8);
        float4 a0 = src[0], a1 = src[1];
        float ss = a0.x*a0.x + a0.y*a0.y + a0.z*a0.z + a0.w*a0.w
                 + a1.x*a1.x + a1.y*a1.y + a1.z*a1.z + a1.w*a1.w;
        ss += __shfl_xor(ss, 1); ss += __shfl_xor(ss, 2);
        ss += __shfl_xor(ss, 4); ss += __shfl_xor(ss, 8);
        half8 hv;
        hv[0] = (_Float16)a0.x; hv[1] = (_Float16)a0.y;
        hv[2] = (_Float16)a0.z; hv[3] = (_Float16)a0.w;
        hv[4] = (_Float16)a1.x; hv[5] = (_Float16)a1.y;
        hv[6] = (_Float16)a1.z; hv[7] = (_Float16)a1.w;
        int phys = l16 ^ ((int)row & 7);
        *(half8*)(qhg + row * CDIM + phys * 8) = hv;
        if (l16 == 0) qssg[row] = ss;
    }
}

// ---------------- Kernel B: keys-in-registers + DMA-staged q (R14) -------------------
// = R12 (86us, proven) with staging replaced by 1 global_load_lds per wave per pair,
// double-buffered by parity, issued one pair ahead. 3 barriers/pair (was 4).
// Rigor chain unchanged: pass2 pushes ALL keys >= thr = M1-2e1-slack (complete list);
// cnt==1 -> exact argmax; cnt>1 -> exact fp32 rescore; cap overflow -> full rescan.
__global__ __launch_bounds__(512, 2) void gather_main(
    const float* __restrict__ q,
    const float* __restrict__ rep,
    const float* __restrict__ keys,
    const float* __restrict__ vals,
    const _Float16* __restrict__ kh,
    const _Float16* __restrict__ qhg,
    const float* __restrict__ qssg,
    float* __restrict__ out)
{
    __shared__ _Float16 qh[2][2][TROWS][128];      // 16 KB: [parity][tile][row][dim]
    __shared__ float wtv[8][2][TROWS];
    __shared__ int   candCnt[32];
    __shared__ int   candKey[32][CANDCAP];
    __shared__ int   rowOvf[32];
    __shared__ unsigned long long rowBest[32];
    __shared__ int   rowIdxAll[BROWS];

    const int t    = threadIdx.x;     // 0..511
    const int w    = t >> 6;          // wave 0..7 (owns keys w*128..w*128+127)
    const int lane = t & 63;
    const int n    = lane & 15;
    const int quad = lane >> 4;
    const long blk0 = (long)blockIdx.x * BROWS;

    // ---- preload this wave's 128 keys into 32 half8 registers (one burst) ----
    const _Float16* kb = kh + (long)w * 16384 + lane * 8;
#define KD(g) k##g##0, k##g##1, k##g##2, k##g##3
    half8 KD(0), KD(1), KD(2), KD(3), KD(4), KD(5), KD(6), KD(7);
#define KL(g) \
    k##g##0 = *(const half8*)(kb + ((g)*4 + 0) * 512); \
    k##g##1 = *(const half8*)(kb + ((g)*4 + 1) * 512); \
    k##g##2 = *(const half8*)(kb + ((g)*4 + 2) * 512); \
    k##g##3 = *(const half8*)(kb + ((g)*4 + 3) * 512);
    KL(0) KL(1) KL(2) KL(3) KL(4) KL(5) KL(6) KL(7)

#define ENCMAX(v_, key_, r_) {                                             \
        FU su; su.f = (v_);                                                \
        unsigned ord = (su.u & 0x80000000u) ? ~su.u : (su.u | 0x80000000u);\
        unsigned long long enc = ((unsigned long long)ord << 32)           \
                               | (unsigned)(1023 - (key_));                \
        atomicMax(&rowBest[r_], enc); }

    // ---- prologue: DMA pair 0 into qh[0]; init state ----
    gl_lds16(qhg + (blk0 + 4 * w) * CDIM + lane * 8,
             &qh[0][0][0][0] + w * 512);
    if (t < 32) { candCnt[t] = 0; rowOvf[t] = 0; rowBest[t] = 0ull; }
    asm volatile("s_waitcnt vmcnt(0)" ::: "memory");
    __syncthreads();

    for (int pair = 0; pair < NPAIRS; ++pair) {
        const int par = pair & 1;
        const long g0 = blk0 + (long)pair * 32;

        // qss prefetch (used after B2; latency hides under pass1)
        float qssA = qssg[g0 + n];
        float qssB = qssg[g0 + 16 + n];

        // ---- B-fragments for row n of both tiles (qh[par] staged by prior DMA) ----
        const int x = n & 7;
        const int fp0 = ((0 * 4 + quad) ^ x) * 8;
        const int fp1 = ((1 * 4 + quad) ^ x) * 8;
        const int fp2 = ((2 * 4 + quad) ^ x) * 8;
        const int fp3 = ((3 * 4 + quad) ^ x) * 8;
        half8 qfA0 = *(const half8*)&qh[par][0][n][fp0];
        half8 qfA1 = *(const half8*)&qh[par][0][n][fp1];
        half8 qfA2 = *(const half8*)&qh[par][0][n][fp2];
        half8 qfA3 = *(const half8*)&qh[par][0][n][fp3];
        half8 qfB0 = *(const half8*)&qh[par][1][n][fp0];
        half8 qfB1 = *(const half8*)&qh[par][1][n][fp1];
        half8 qfB2 = *(const half8*)&qh[par][1][n][fp2];
        half8 qfB3 = *(const half8*)&qh[par][1][n][fp3];

        // ---- pass 1: 64-MFMA slab over both tiles; per-lane max ----
        float m1A = -3.4e38f, m1B = -3.4e38f;
#define P1AB(g) {                                                            \
        floatx4 aA = {0.f,0.f,0.f,0.f}, aB = {0.f,0.f,0.f,0.f};              \
        aA = MFMA16(k##g##0, qfA0, aA, 0, 0, 0);                             \
        aB = MFMA16(k##g##0, qfB0, aB, 0, 0, 0);                             \
        aA = MFMA16(k##g##1, qfA1, aA, 0, 0, 0);                             \
        aB = MFMA16(k##g##1, qfB1, aB, 0, 0, 0);                             \
        aA = MFMA16(k##g##2, qfA2, aA, 0, 0, 0);                             \
        aB = MFMA16(k##g##2, qfB2, aB, 0, 0, 0);                             \
        aA = MFMA16(k##g##3, qfA3, aA, 0, 0, 0);                             \
        aB = MFMA16(k##g##3, qfB3, aB, 0, 0, 0);                             \
        m1A = fmaxf(m1A, fmaxf(fmaxf(aA[0], aA[1]), fmaxf(aA[2], aA[3])));   \
        m1B = fmaxf(m1B, fmaxf(fmaxf(aB[0], aB[1]), fmaxf(aB[2], aB[3]))); }
        P1AB(0) P1AB(1) P1AB(2) P1AB(3) P1AB(4) P1AB(5) P1AB(6) P1AB(7)
        m1A = fmaxf(m1A, __shfl_xor(m1A, 16));
        m1A = fmaxf(m1A, __shfl_xor(m1A, 32));
        m1B = fmaxf(m1B, __shfl_xor(m1B, 16));
        m1B = fmaxf(m1B, __shfl_xor(m1B, 32));
        if (lane < TROWS) { wtv[w][0][n] = m1A; wtv[w][1][n] = m1B; }
        __syncthreads();                                               // B2

        // ---- DMA next pair's q into qh[par^1] (drains at B3, hidden) ----
        if (pair + 1 < NPAIRS) {
            gl_lds16(qhg + (g0 + 32 + 4 * w) * CDIM + lane * 8,
                     &qh[par ^ 1][0][0][0] + w * 512);
        }

        // ---- thresholds, computed redundantly by every thread for its row n ----
        float M1A = wtv[0][0][n], M1B = wtv[0][1][n];
        #pragma unroll
        for (int ww = 1; ww < 8; ++ww) {
            M1A = fmaxf(M1A, wtv[ww][0][n]);
            M1B = fmaxf(M1B, wtv[ww][1][n]);
        }
        // fp16 rounding: |s~ - s| <= 2^-10*1.01*||q||*||k||max(<=17) + slack
        float thrA = M1A - 2.f * (0.0168f * sqrtf(qssA) + 0.002f) - 0.02f;
        float thrB = M1B - 2.f * (0.0168f * sqrtf(qssB) + 0.002f) - 0.02f;

        // ---- pass 2: bit-identical recompute; push ALL keys >= thr ----
#define PUSHK(r_, K_) { int pp_ = atomicAdd(&candCnt[r_], 1);                \
        if (pp_ < CANDCAP) candKey[r_][pp_] = (K_); else rowOvf[r_] = 1; }
#define P2AB(g) {                                                            \
        floatx4 aA = {0.f,0.f,0.f,0.f}, aB = {0.f,0.f,0.f,0.f};              \
        aA = MFMA16(k##g##0, qfA0, aA, 0, 0, 0);                             \
        aB = MFMA16(k##g##0, qfB0, aB, 0, 0, 0);                             \
        aA = MFMA16(k##g##1, qfA1, aA, 0, 0, 0);                             \
        aB = MFMA16(k##g##1, qfB1, aB, 0, 0, 0);                             \
        aA = MFMA16(k##g##2, qfA2, aA, 0, 0, 0);                             \
        aB = MFMA16(k##g##2, qfB2, aB, 0, 0, 0);                             \
        aA = MFMA16(k##g##3, qfA3, aA, 0, 0, 0);                             \
        aB = MFMA16(k##g##3, qfB3, aB, 0, 0, 0);                             \
        int keyb = ((w * 8 + (g)) << 4) + (quad << 2);                       \
        if (aA[0] >= thrA) PUSHK(n, keyb);                                   \
        if (aA[1] >= thrA) PUSHK(n, keyb + 1);                               \
        if (aA[2] >= thrA) PUSHK(n, keyb + 2);                               \
        if (aA[3] >= thrA) PUSHK(n, keyb + 3);                               \
        if (aB[0] >= thrB) PUSHK(16 + n, keyb);                              \
        if (aB[1] >= thrB) PUSHK(16 + n, keyb + 1);                          \
        if (aB[2] >= thrB) PUSHK(16 + n, keyb + 2);                          \
        if (aB[3] >= thrB) PUSHK(16 + n, keyb + 3); }
        P2AB(0) P2AB(1) P2AB(2) P2AB(3) P2AB(4) P2AB(5) P2AB(6) P2AB(7)
        __syncthreads();                                               // B3

        // ---- ballot-gated sparse exact resolve ----
        {
            int r32 = lane & 31;
            int cntL = candCnt[r32], ovL = rowOvf[r32];
            unsigned long long needMask = __ballot(!ovL && cntL > 1) & 0xffffffffull;
            unsigned long long ovfMask  = __ballot(ovL != 0) & 0xffffffffull;
            while (needMask) {
                int rb = __builtin_ctzll(needMask); needMask &= needMask - 1;
                if (w < candCnt[rb]) {
                    int key = candKey[rb][w];
                    const float2 xq = *(const float2*)(q + (g0 + rb) * CDIM + lane * 2);
                    const float2 xk = *(const float2*)(keys + (long)key * CDIM + lane * 2);
                    float v = xq.x * xk.x + xq.y * xk.y;
                    v += __shfl_xor(v, 1);  v += __shfl_xor(v, 2);
                    v += __shfl_xor(v, 4);  v += __shfl_xor(v, 8);
                    v += __shfl_xor(v, 16); v += __shfl_xor(v, 32);
                    if (lane == 0) ENCMAX(v, key, rb);
                }
            }
            while (ovfMask) {
                int rb = __builtin_ctzll(ovfMask); ovfMask &= ovfMask - 1;
                int grp = t >> 4, l16 = t & 15;
                const float* qp = q + (g0 + rb) * CDIM + l16 * 8;
                float4 xa = *(const float4*)(qp), xb = *(const float4*)(qp + 4);
                for (int it = 0; it < 32; ++it) {
                    int key = it * 32 + grp;
                    const float* kp2 = keys + (long)key * CDIM + l16 * 8;
                    float4 ya = *(const float4*)(kp2), yb = *(const float4*)(kp2 + 4);
                    float v = xa.x*ya.x + xa.y*ya.y + xa.z*ya.z + xa.w*ya.w
                            + xb.x*yb.x + xb.y*yb.y + xb.z*yb.z + xb.w*yb.w;
                    v += __shfl_xor(v, 1); v += __shfl_xor(v, 2);
                    v += __shfl_xor(v, 4); v += __shfl_xor(v, 8);
                    if (l16 == 0) ENCMAX(v, key, rb);
                }
            }
        }
        __syncthreads();                                               // B4

        // ---- decode + reset (owner thread; next pushes are after next B2) ----
        if (t < 32) {
            int cnt = candCnt[t];
            rowIdxAll[pair * 32 + t] =
                (!rowOvf[t] && cnt == 1)
                    ? candKey[t][0]
                    : (1023 - (int)(unsigned)(rowBest[t] & 0xffffffffull));
            candCnt[t] = 0; rowOvf[t] = 0; rowBest[t] = 0ull;
        }
    }
    __syncthreads();

    // ---- batched gather: 8 passes x 32 rows, 16 lanes per row ----
    {
        int l16 = t & 15;
        #pragma unroll 1
        for (int pass = 0; pass < BROWS / 32; ++pass) {
            int row = pass * 32 + (t >> 4);
            int idx = rowIdxAll[row];
            long g = blk0 + row;
            const float* qp  = q    + g * CDIM + l16 * 8;
            const float* kp2 = keys + (long)idx * CDIM + l16 * 8;
            const float* rp  = rep  + g * CDIM + l16 * 8;
            const float* vp  = vals + (long)idx * CDIM + l16 * 8;
            float4 qa = *(const float4*)(qp),  qb = *(const float4*)(qp + 4);
            float4 ka = *(const float4*)(kp2), kb4 = *(const float4*)(kp2 + 4);
            float4 ra = *(const float4*)(rp),  rb = *(const float4*)(rp + 4);
            float4 va = *(const float4*)(vp),  vb = *(const float4*)(vp + 4);
            float d0 = qa.x-ka.x, d1 = qa.y-ka.y, d2 = qa.z-ka.z, d3 = qa.w-ka.w;
            float d4 = qb.x-kb4.x, d5 = qb.y-kb4.y, d6 = qb.z-kb4.z, d7 = qb.w-kb4.w;
            float kg = d0*d0+d1*d1+d2*d2+d3*d3+d4*d4+d5*d5+d6*d6+d7*d7;
            float e0 = ra.x-va.x, e1 = ra.y-va.y, e2 = ra.z-va.z, e3 = ra.w-va.w;
            float e4 = rb.x-vb.x, e5 = rb.y-vb.y, e6 = rb.z-vb.z, e7 = rb.w-vb.w;
            float vg = e0*e0+e1*e1+e2*e2+e3*e3+e4*e4+e5*e5+e6*e6+e7*e7;
            kg += __shfl_xor(kg, 1); kg += __shfl_xor(kg, 2);
            kg += __shfl_xor(kg, 4); kg += __shfl_xor(kg, 8);
            vg += __shfl_xor(vg, 1); vg += __shfl_xor(vg, 2);
            vg += __shfl_xor(vg, 4); vg += __shfl_xor(vg, 8);
            if (l16 == 0) { out[g] = kg; out[NROWS + g] = vg; }
        }
    }
}

// ---------------- Fallback: exact R12 kernel (used if workspace too small) -----------
__global__ __launch_bounds__(512, 2) void gather_main_fb(
    const float* __restrict__ q, const float* __restrict__ rep,
    const float* __restrict__ keys, const float* __restrict__ vals,
    const _Float16* __restrict__ kh, float* __restrict__ out)
{
    __shared__ _Float16 qh[2][TROWS][128];
    __shared__ float qss[2][TROWS][17];
    __shared__ float wtv[8][2][TROWS];
    __shared__ int   candCnt[32];
    __shared__ int   candKey[32][CANDCAP];
    __shared__ int   rowOvf[32];
    __shared__ unsigned long long rowBest[32];
    __shared__ int   rowIdxAll[BROWS];

    const int t = threadIdx.x, w = t >> 6, lane = t & 63;
    const int n = lane & 15, quad = lane >> 4;
    const long blk0 = (long)blockIdx.x * BROWS;

    const _Float16* kb = kh + (long)w * 16384 + lane * 8;
    half8 KD(0), KD(1), KD(2), KD(3), KD(4), KD(5), KD(6), KD(7);
    KL(0) KL(1) KL(2) KL(3) KL(4) KL(5) KL(6) KL(7)

    for (int pair = 0; pair < NPAIRS; ++pair) {
        const long g0 = blk0 + (long)pair * 32;
        {
            int half = t >> 8, tt = t & 255;
            int row = tt >> 4, c8 = tt & 15;
            const float4* src =
                (const float4*)(q + (g0 + half * TROWS + row) * CDIM + c8 * 8);
            float4 a0 = src[0], a1 = src[1];
            qss[half][row][c8] = a0.x*a0.x + a0.y*a0.y + a0.z*a0.z + a0.w*a0.w
                               + a1.x*a1.x + a1.y*a1.y + a1.z*a1.z + a1.w*a1.w;
            half8 hv;
            hv[0] = (_Float16)a0.x; hv[1] = (_Float16)a0.y;
            hv[2] = (_Float16)a0.z; hv[3] = (_Float16)a0.w;
            hv[4] = (_Float16)a1.x; hv[5] = (_Float16)a1.y;
            hv[6] = (_Float16)a1.z; hv[7] = (_Float16)a1.w;
            int phys = c8 ^ (row & 7);
            *(half8*)&qh[half][row][phys * 8] = hv;
            if (t < 32) { candCnt[t] = 0; rowOvf[t] = 0; rowBest[t] = 0ull; }
        }
        __syncthreads();
        int x = n & 7;
        int p0 = ((0 * 4 + quad) ^ x) * 8, p1 = ((1 * 4 + quad) ^ x) * 8;
        int p2 = ((2 * 4 + quad) ^ x) * 8, p3 = ((3 * 4 + quad) ^ x) * 8;
        half8 qfA0 = *(const half8*)&qh[0][n][p0];
        half8 qfA1 = *(const half8*)&qh[0][n][p1];
        half8 qfA2 = *(const half8*)&qh[0][n][p2];
        half8 qfA3 = *(const half8*)&qh[0][n][p3];
        half8 qfB0 = *(const half8*)&qh[1][n][p0];
        half8 qfB1 = *(const half8*)&qh[1][n][p1];
        half8 qfB2 = *(const half8*)&qh[1][n][p2];
        half8 qfB3 = *(const half8*)&qh[1][n][p3];
        float m1A = -3.4e38f, m1B = -3.4e38f;
        P1AB(0) P1AB(1) P1AB(2) P1AB(3) P1AB(4) P1AB(5) P1AB(6) P1AB(7)
        m1A = fmaxf(m1A, __shfl_xor(m1A, 16));
        m1A = fmaxf(m1A, __shfl_xor(m1A, 32));
        m1B = fmaxf(m1B, __shfl_xor(m1B, 16));
        m1B = fmaxf(m1B, __shfl_xor(m1B, 32));
        if (lane < TROWS) { wtv[w][0][n] = m1A; wtv[w][1][n] = m1B; }
        __syncthreads();
        float M1A = wtv[0][0][n], M1B = wtv[0][1][n];
        #pragma unroll
        for (int ww = 1; ww < 8; ++ww) {
            M1A = fmaxf(M1A, wtv[ww][0][n]);
            M1B = fmaxf(M1B, wtv[ww][1][n]);
        }
        float qn2A = 0.f, qn2B = 0.f;
        #pragma unroll
        for (int j = 0; j < 16; ++j) { qn2A += qss[0][n][j]; qn2B += qss[1][n][j]; }
        float thrA = M1A - 2.f * (0.0168f * sqrtf(qn2A) + 0.002f) - 0.02f;
        float thrB = M1B - 2.f * (0.0168f * sqrtf(qn2B) + 0.002f) - 0.02f;
        P2AB(0) P2AB(1) P2AB(2) P2AB(3) P2AB(4) P2AB(5) P2AB(6) P2AB(7)
        __syncthreads();
        {
            int r32 = lane & 31;
            int cntL = candCnt[r32], ovL = rowOvf[r32];
            unsigned long long needMask = __ballot(!ovL && cntL > 1) & 0xffffffffull;
            unsigned long long ovfMask  = __ballot(ovL != 0) & 0xffffffffull;
            while (needMask) {
                int rb = __builtin_ctzll(needMask); needMask &= needMask - 1;
                if (w < candCnt[rb]) {
                    int key = candKey[rb][w];
                    const float2 xq = *(const float2*)(q + (g0 + rb) * CDIM + lane * 2);
                    const float2 xk = *(const float2*)(keys + (long)key * CDIM + lane * 2);
                    float v = xq.x * xk.x + xq.y * xk.y;
                    v += __shfl_xor(v, 1);  v += __shfl_xor(v, 2);
                    v += __shfl_xor(v, 4);  v += __shfl_xor(v, 8);
                    v += __shfl_xor(v, 16); v += __shfl_xor(v, 32);
                    if (lane == 0) ENCMAX(v, key, rb);
                }
            }
            while (ovfMask) {
                int rb = __builtin_ctzll(ovfMask); ovfMask &= ovfMask - 1;
                int grp = t >> 4, l16 = t & 15;
                const float* qp = q + (g0 + rb) * CDIM + l16 * 8;
                float4 xa = *(const float4*)(qp), xb = *(const float4*)(qp + 4);
                for (int it = 0; it < 32; ++it) {
                    int key = it * 32 + grp;
                    const float* kp2 = keys + (long)key * CDIM + l16 * 8;
                    float4 ya = *(const float4*)(kp2), yb = *(const float4*)(kp2 + 4);
                    float v = xa.x*ya.x + xa.y*ya.y + xa.z*ya.z + xa.w*ya.w
                            + xb.x*yb.x + xb.y*yb.y + xb.z*yb.z + xb.w*yb.w;
                    v += __shfl_xor(v, 1); v += __shfl_xor(v, 2);
                    v += __shfl_xor(v, 4); v += __shfl_xor(v, 8);
                    if (l16 == 0) ENCMAX(v, key, rb);
                }
            }
        }
        __syncthreads();
        if (t < 32) {
            int cnt = candCnt[t];
            rowIdxAll[pair * 32 + t] =
                (!rowOvf[t] && cnt == 1)
                    ? candKey[t][0]
                    : (1023 - (int)(unsigned)(rowBest[t] & 0xffffffffull));
        }
    }
    __syncthreads();
    {
        int l16 = t & 15;
        #pragma unroll 1
        for (int pass = 0; pass < BROWS / 32; ++pass) {
            int row = pass * 32 + (t >> 4);
            int idx = rowIdxAll[row];
            long g = blk0 + row;
            const float* qp  = q    + g * CDIM + l16 * 8;
            const float* kp2 = keys + (long)idx * CDIM + l16 * 8;
            const float* rp  = rep  + g * CDIM + l16 * 8;
            const float* vp  = vals + (long)idx * CDIM + l16 * 8;
            float4 qa = *(const float4*)(qp),  qb = *(const float4*)(qp + 4);
            float4 ka = *(const float4*)(kp2), kb4 = *(const float4*)(kp2 + 4);
            float4 ra = *(const float4*)(rp),  rb = *(const float4*)(rp + 4);
            float4 va = *(const float4*)(vp),  vb = *(const float4*)(vp + 4);
            float d0 = qa.x-ka.x, d1 = qa.y-ka.y, d2 = qa.z-ka.z, d3 = qa.w-ka.w;
            float d4 = qb.x-kb4.x, d5 = qb.y-kb4.y, d6 = qb.z-kb4.z, d7 = qb.w-kb4.w;
            float kg = d0*d0+d1*d1+d2*d2+d3*d3+d4*d4+d5*d5+d6*d6+d7*d7;
            float e0 = ra.x-va.x, e1 = ra.y-va.y, e2 = ra.z-va.z, e3 = ra.w-va.w;
            float e4 = rb.x-vb.x, e5 = rb.y-vb.y, e6 = rb.z-vb.z, e7 = rb.w-vb.w;
            float vg = e0*e0+e1*e1+e2*e2+e3*e3+e4*e4+e5*e5+e6*e6+e7*e7;
            kg += __shfl_xor(kg, 1); kg += __shfl_xor(kg, 2);
            kg += __shfl_xor(kg, 4); kg += __shfl_xor(kg, 8);
            vg += __shfl_xor(vg, 1); vg += __shfl_xor(vg, 2);
            vg += __shfl_xor(vg, 4); vg += __shfl_xor(vg, 8);
            if (l16 == 0) { out[g] = kg; out[NROWS + g] = vg; }
        }
    }
}

extern "C" void kernel_launch(void* const* d_in, const int* in_sizes, int n_in,
                              void* d_out, int out_size, void* d_ws, size_t ws_size,
                              hipStream_t stream) {
    const float* q    = (const float*)d_in[0];  // trend_representation
    const float* rep  = (const float*)d_in[1];  // representation
    const float* keys = (const float*)d_in[2];
    const float* vals = (const float*)d_in[3];
    _Float16* kh = (_Float16*)d_ws;             // 256 KB fp16 key cache

    const size_t KH_BYTES  = 256 * 1024;
    const size_t QHG_BYTES = (size_t)NROWS * CDIM * sizeof(_Float16);   // 16 MB
    const size_t QSS_BYTES = (size_t)NROWS * sizeof(float);             // 256 KB

    if (ws_size >= KH_BYTES + QHG_BYTES + QSS_BYTES) {
        _Float16* qhg = (_Float16*)((char*)d_ws + KH_BYTES);
        float* qssg   = (float*)((char*)d_ws + KH_BYTES + QHG_BYTES);
        cvt_kernel<<<128 + NROWS / 16, 256, 0, stream>>>(keys, q, kh, qhg, qssg);
        gather_main<<<NROWS / BROWS, 512, 0, stream>>>(q, rep, keys, vals, kh,
                                                       qhg, qssg, (float*)d_out);
    } else {
        cvt_kernel<<<128, 256, 0, stream>>>(keys, q, kh, nullptr, nullptr);
        gather_main_fb<<<NROWS / BROWS, 512, 0, stream>>>(q, rep, keys, vals, kh,
                                                          (float*)d_out);
    }
}